// Round 3
// baseline (352.368 us; speedup 1.0000x reference)
//
#include <hip/hip_runtime.h>

// Problem constants (B=8, Cin=O=16, group=12, H=64)
#define NB   8
#define NIC  192        // Cin*12
#define NOC  192        // O*12
#define HP   66
#define WP   322
#define HPWP (HP * WP)

typedef _Float16 f16x8 __attribute__((ext_vector_type(8)));
typedef float    f32x4 __attribute__((ext_vector_type(4)));

// Swizzled weights: [icc6][tap7][(mi*2+wn)12][lane64][j8]  (516 KB) — L2-resident.
__device__ __align__(16) _Float16 g_Ks[6 * 7 * 12 * 64 * 8];
// Transposed f16 x: [b8][icc6][y66][kg4][col322][j8]  (65.3 MB)
__device__ __align__(16) _Float16 g_xt[NB * 6 * 66 * 4 * 322 * 8];

#define ICCH  (66 * 4 * 322 * 8)   // halfs per (b,icc) slice of g_xt
#define SLABH (12 * 64 * 8)        // halfs per tap slab of g_Ks (6144)

// ---------------------------------------------------------------------------
// Kernel 1: expand weight (O,Cin,12,7) -> g_Ks (f16, MFMA-A-swizzled).
// Slab layout: entry for (kg, oc) lives at [(mi*2+wn)][lane=kg*16+n15][j],
// mi=(oc%96)/16, wn=oc/96, n15=oc%16 -> wave ds_read_b128 is 1KB contiguous.
// ---------------------------------------------------------------------------
__global__ void prep_kernel(const float* __restrict__ w) {
    int tid = blockIdx.x * 256 + threadIdx.x;
    if (tid >= 7 * NOC * NIC) return;
    int ic = tid % NIC;
    int rest = tid / NIC;
    int oc = rest % NOC;
    int t = rest / NOC;
    int o = oc / 12, g = oc % 12;
    int c = ic / 12, h = ic % 12;
    int f = g / 6, r = g % 6;
    int ri = (f == 0) ? (6 - r) % 6 : r;          // inv(g).r
    int fh = h / 6, rh = h % 6;
    int pf = f ^ fh;
    int pr = (f == 0) ? (ri + rh) % 6 : (ri - rh + 6) % 6;
    int pm = pf * 6 + pr;                          // perm[g][h]
    const float* wsrc = w + ((o * 16 + c) * 12 + pm) * 7;
    float v;
    if (t == 0) {
        v = wsrc[0];
    } else {
        int i = t - 1;
        int s = (f == 0) ? (i - r + 6) % 6 : (r - i + 6) % 6;
        v = wsrc[1 + s];
    }
    int icc = ic >> 5, kg = (ic >> 3) & 3, j = ic & 7;
    int wn2 = oc / 96, mi = (oc % 96) / 16, n15 = oc % 16;
    g_Ks[((((icc * 7) + t) * 12 + mi * 2 + wn2) * 64 + kg * 16 + n15) * 8 + j]
        = (_Float16)v;
}

// ---------------------------------------------------------------------------
// Kernel 2: transpose x (fp32 [b][ic][y][col]) -> g_xt [b][icc][y][kg][col][j8].
// Wave = one kg (8 channels); lane = column. Loads: 64 consecutive floats per
// plane per instr (256B). Stores: 64 lanes x 16B = 1KB contiguous. No LDS.
// ---------------------------------------------------------------------------
__global__ __launch_bounds__(256) void transpose_kernel(const float* __restrict__ x) {
    int id  = blockIdx.x;                 // 8*6*66 = 3168 blocks
    int y   = id % 66;
    int icc = (id / 66) % 6;
    int b   = id / 396;
    int kg   = threadIdx.x >> 6;
    int lane = threadIdx.x & 63;
    const float* src0 = x + ((size_t)b * NIC + icc * 32 + kg * 8) * HPWP + (size_t)y * WP;
    _Float16* dst = g_xt + ((((size_t)(b * 6 + icc) * 66 + y) * 4 + kg) * 322) * 8;
#pragma unroll
    for (int p = 0; p < 6; p++) {
        int col = lane + p * 64;
        if (p < 5 || col < 322) {
            union { f16x8 v8; _Float16 h[8]; } u;
#pragma unroll
            for (int j = 0; j < 8; j++)
                u.h[j] = (_Float16)src0[(size_t)j * HPWP + col];
            *(f16x8*)&dst[col * 8] = u.v8;
        }
    }
}

// ---------------------------------------------------------------------------
// Kernel 3: MFMA implicit-GEMM conv, software-pipelined LDS staging.
// A (weights): 3 rotating tap slabs, staged TWO steps ahead (post-barrier
// issue makes the t+2 target buffer race-free with 3 buffers).
// B (x): double-buffered per-icc slab [row4][kg4][col66][j8] (+64-slot pad).
// One s_barrier per tap-step; counted vmcnt (never 0 mid-loop); setprio.
// Hex taps (hy,hx): 0:(1,1) 1:(0,0) 2:(0,1) 3:(1,2) 4:(2,2) 5:(2,1) 6:(1,0)
// ---------------------------------------------------------------------------
__device__ __forceinline__ void gload16(const _Float16* g, _Float16* l) {
    __builtin_amdgcn_global_load_lds(
        (const __attribute__((address_space(1))) void*)g,
        (__attribute__((address_space(3))) void*)l, 16, 0, 0);
}

__global__ __launch_bounds__(256, 2) void conv_kernel(
    const float* __restrict__ bias, float* __restrict__ out) {
    __shared__ __align__(16) _Float16 lA[3][SLABH];  // 3 x 12,288B tap slabs
    __shared__ __align__(16) _Float16 lB[2][8960];   // 2 x 17,920B (1056+64 pad)

    int id = blockIdx.x;                  // 1280 blocks = 8 XCD * 160
    id = (id & 7) * 160 + (id >> 3);      // bijective XCD swizzle: XCD i owns b=i
    int xt5 = id % 5;
    int yt = (id / 5) % 32;
    int b  = id / 160;
    int px0 = xt5 * 64, py0 = yt * 2;

    int tid = threadIdx.x;
    int wave = tid >> 6;
    int lane = tid & 63;
    int kg = lane >> 4, n15 = lane & 15;
    int wm = wave & 1;                    // output row py0+1+wm
    int wn = wave >> 1;                   // oc half (wn*96)

    const _Float16* xtb = g_xt + (size_t)b * (6 * ICCH);

    // Precompute B-stage slot decompositions (icc-invariant). 5 uniform issues.
    int gbo[5], lso[5];
#pragma unroll
    for (int k = 0; k < 5; k++) {
        int slot = tid + k * 256;
        if (slot > 1055) slot = 1055;     // clamp: pad region absorbs overflow
        int row = slot / 264;
        int rem = slot % 264;
        int kg2 = rem / 66;
        int col = rem % 66;
        gbo[k] = (((py0 + row) * 4 + kg2) * 322 + px0 + col) * 8;
        lso[k] = slot * 8;
    }

    f32x4 acc[6][4] = {};                 // [oc group][pixel group]

#define WV3 asm volatile("s_waitcnt vmcnt(3)" ::: "memory")
#define WV8 asm volatile("s_waitcnt vmcnt(8)" ::: "memory")
#define WV0 asm volatile("s_waitcnt vmcnt(0)" ::: "memory")

#define ABUF(T) ((T) % 3 == 0 ? ia0 : ((T) % 3 == 1 ? ia1 : ia2))
#define ASTG(T) (((T)+2) % 3 == 0 ? ia0 : (((T)+2) % 3 == 1 ? ia1 : ia2))

#define COMPUTE(T, HYv, HXv)                                                   \
    {                                                                          \
        const _Float16* bb = &lB[bi][(((wm + (HYv)) * 4 + kg) * 66 +           \
                                      (HXv) + n15) * 8];                       \
        f16x8 xf[4];                                                           \
        _Pragma("unroll")                                                      \
        for (int ni = 0; ni < 4; ni++)                                         \
            xf[ni] = *(const f16x8*)(bb + ni * (16 * 8));                      \
        __builtin_amdgcn_s_setprio(1);                                         \
        _Pragma("unroll")                                                      \
        for (int mi = 0; mi < 6; mi++) {                                       \
            f16x8 wf = *(const f16x8*)                                         \
                &lA[ABUF(T)][((mi * 2 + wn) * 64 + lane) * 8];                 \
            _Pragma("unroll")                                                  \
            for (int ni = 0; ni < 4; ni++)                                     \
                acc[mi][ni] = __builtin_amdgcn_mfma_f32_16x16x32_f16(          \
                    wf, xf[ni], acc[mi][ni], 0, 0, 0);                         \
        }                                                                      \
        __builtin_amdgcn_s_setprio(0);                                         \
    }

// Step order: wait(A[t] arrived, issued 2 steps ago) -> barrier -> issue
// A[t+2] (and B[icc+1] at t==4) -> compute(t). All issue counts wave-uniform.
#define STEP(T, WVBLK, HYv, HXv)                                               \
    {                                                                          \
        WVBLK;                                                                 \
        __builtin_amdgcn_s_barrier();                                          \
        __builtin_amdgcn_sched_barrier(0);                                     \
        if ((T) < 5 || icc < 5) {  /* stage A for step T+2 (g_Ks contiguous) */\
            const _Float16* asrc = kb + ((T) + 2) * SLABH;                     \
            gload16(asrc + (tid + 0 * 256) * 8,                                \
                    &lA[ASTG(T)][(tid + 0 * 256) * 8]);                        \
            gload16(asrc + (tid + 1 * 256) * 8,                                \
                    &lA[ASTG(T)][(tid + 1 * 256) * 8]);                        \
            gload16(asrc + (tid + 2 * 256) * 8,                                \
                    &lA[ASTG(T)][(tid + 2 * 256) * 8]);                        \
        }                                                                      \
        if ((T) == 4 && icc < 5) {  /* stage B for next icc */                 \
            const _Float16* bsrc = xtb + (size_t)(icc + 1) * ICCH;             \
            gload16(bsrc + gbo[0], &lB[bi ^ 1][lso[0]]);                       \
            gload16(bsrc + gbo[1], &lB[bi ^ 1][lso[1]]);                       \
            gload16(bsrc + gbo[2], &lB[bi ^ 1][lso[2]]);                       \
            gload16(bsrc + gbo[3], &lB[bi ^ 1][lso[3]]);                       \
            gload16(bsrc + gbo[4], &lB[bi ^ 1][lso[4]]);                       \
        }                                                                      \
        __builtin_amdgcn_sched_barrier(0);                                     \
        COMPUTE(T, HYv, HXv);                                                  \
    }

    int ia0 = 0, ia1 = 1, ia2 = 2;
    int bi = 0;

    // Prologue: B[icc0] first (FIFO-oldest), then A[0]->buf0, A[1]->buf1.
    {
        const _Float16* bsrc = xtb;
        gload16(bsrc + gbo[0], &lB[0][lso[0]]);
        gload16(bsrc + gbo[1], &lB[0][lso[1]]);
        gload16(bsrc + gbo[2], &lB[0][lso[2]]);
        gload16(bsrc + gbo[3], &lB[0][lso[3]]);
        gload16(bsrc + gbo[4], &lB[0][lso[4]]);
        gload16(g_Ks + (tid + 0 * 256) * 8, &lA[0][(tid + 0 * 256) * 8]);
        gload16(g_Ks + (tid + 1 * 256) * 8, &lA[0][(tid + 1 * 256) * 8]);
        gload16(g_Ks + (tid + 2 * 256) * 8, &lA[0][(tid + 2 * 256) * 8]);
        gload16(g_Ks + SLABH + (tid + 0 * 256) * 8, &lA[1][(tid + 0 * 256) * 8]);
        gload16(g_Ks + SLABH + (tid + 1 * 256) * 8, &lA[1][(tid + 1 * 256) * 8]);
        gload16(g_Ks + SLABH + (tid + 2 * 256) * 8, &lA[1][(tid + 2 * 256) * 8]);
    }

    for (int icc = 0; icc < 6; icc++) {
        const _Float16* kb = g_Ks + icc * (7 * SLABH);
        STEP(0, WV3, 1, 1);
        STEP(1, WV3, 0, 0);
        STEP(2, WV3, 0, 1);
        STEP(3, WV3, 1, 2);
        STEP(4, WV3, 2, 2);
        STEP(5, { if (icc < 5) { WV8; } else { WV3; } }, 2, 1);
        STEP(6, { if (icc < 5) { WV8; } else { WV0; } }, 1, 0);
        { int tt = ia0; ia0 = ia1; ia1 = ia2; ia2 = tt; }
        bi ^= 1;
    }
#undef STEP
#undef COMPUTE
#undef ABUF
#undef ASTG

    // ---- epilogue: +bias, write interior rows ----
    int yo = py0 + 1 + wm;
#pragma unroll
    for (int mi = 0; mi < 6; mi++) {
#pragma unroll
        for (int reg = 0; reg < 4; reg++) {
            int oc = wn * 96 + mi * 16 + kg * 4 + reg;
            float bv = bias[oc / 12];
            size_t base = ((size_t)(b * NOC + oc) * HP + yo) * WP + 1 + px0 + n15;
#pragma unroll
            for (int ni = 0; ni < 4; ni++)
                out[base + ni * 16] = acc[mi][ni][reg] + bv;
        }
    }
}

// ---------------------------------------------------------------------------
// Kernel 4: fill the 1-px ring via twisted-periodic gather from interior.
// ---------------------------------------------------------------------------
__global__ void border_kernel(float* __restrict__ out) {
    int tid = blockIdx.x * 256 + threadIdx.x;   // < 8*192*772 = 1185792
    int r  = tid % 772;
    int bc = tid / 772;
    int ch = bc % NOC;
    int b  = bc / NOC;
    int y, xx;
    if (r < 322)      { y = 0;  xx = r; }
    else if (r < 644) { y = 65; xx = r - 322; }
    else if (r < 708) { xx = 0;   y = r - 644 + 1; }
    else              { xx = 321; y = r - 708 + 1; }
    int t = ch % 12;
    int o12 = ch - t;
    int f = t / 6, rr = t % 6;
    int dt = (xx == 0) ? 1 : ((xx == 321) ? -1 : 0);
    int sx = (xx == 0) ? 320 : ((xx == 321) ? 1 : xx);
    int sy = (y == 0) ? 64 : ((y == 65) ? 1 : y);
    int tsrc = f * 6 + (rr + dt + 6) % 6;
    float v = out[((size_t)(b * NOC + o12 + tsrc) * HP + sy) * WP + sx];
    out[((size_t)(b * NOC + ch) * HP + y) * WP + xx] = v;
}

extern "C" void kernel_launch(void* const* d_in, const int* in_sizes, int n_in,
                              void* d_out, int out_size, void* d_ws, size_t ws_size,
                              hipStream_t stream) {
    const float* x    = (const float*)d_in[0];
    const float* w    = (const float*)d_in[1];
    const float* bias = (const float*)d_in[2];
    float* out = (float*)d_out;

    prep_kernel<<<(7 * NOC * NIC + 255) / 256, 256, 0, stream>>>(w);
    transpose_kernel<<<NB * 6 * 66, 256, 0, stream>>>(x);
    conv_kernel<<<1280, 256, 0, stream>>>(bias, out);
    border_kernel<<<(NB * NOC * 772) / 256, 256, 0, stream>>>(out);
}

// Round 4
// 323.188 us; speedup vs baseline: 1.0903x; 1.0903x over previous
//
#include <hip/hip_runtime.h>

// Problem constants (B=8, Cin=O=16, group=12, H=64)
#define NB   8
#define NIC  192        // Cin*12
#define NOC  192        // O*12
#define HP   66
#define WP   322
#define HPWP (HP * WP)

typedef _Float16 f16x8 __attribute__((ext_vector_type(8)));
typedef float    f32x4 __attribute__((ext_vector_type(4)));

// Swizzled weights: [icc6][tap7][(mi*2+wn)12][lane64][j8]  (516 KB) — L2-resident.
__device__ __align__(16) _Float16 g_Ks[6 * 7 * 12 * 64 * 8];
// Transposed f16 x: [b8][icc6][y66][kg4][col322][j8]  (65.3 MB)
__device__ __align__(16) _Float16 g_xt[NB * 6 * 66 * 4 * 322 * 8];

#define ICCH  (66 * 4 * 322 * 8)   // halfs per (b,icc) slice of g_xt
#define SLABH (12 * 64 * 8)        // halfs per tap slab of g_Ks (6144)

// ---------------------------------------------------------------------------
// Kernel 1: expand weight (O,Cin,12,7) -> g_Ks (f16, MFMA-A-swizzled).
// Slab layout: entry for (kg, oc) lives at [(mi*2+wn)][lane=kg*16+n15][j],
// mi=(oc%96)/16, wn=oc/96, n15=oc%16 -> per-wave A-frag load is 1KB contiguous.
// ---------------------------------------------------------------------------
__global__ void prep_kernel(const float* __restrict__ w) {
    int tid = blockIdx.x * 256 + threadIdx.x;
    if (tid >= 7 * NOC * NIC) return;
    int ic = tid % NIC;
    int rest = tid / NIC;
    int oc = rest % NOC;
    int t = rest / NOC;
    int o = oc / 12, g = oc % 12;
    int c = ic / 12, h = ic % 12;
    int f = g / 6, r = g % 6;
    int ri = (f == 0) ? (6 - r) % 6 : r;          // inv(g).r
    int fh = h / 6, rh = h % 6;
    int pf = f ^ fh;
    int pr = (f == 0) ? (ri + rh) % 6 : (ri - rh + 6) % 6;
    int pm = pf * 6 + pr;                          // perm[g][h]
    const float* wsrc = w + ((o * 16 + c) * 12 + pm) * 7;
    float v;
    if (t == 0) {
        v = wsrc[0];
    } else {
        int i = t - 1;
        int s = (f == 0) ? (i - r + 6) % 6 : (r - i + 6) % 6;
        v = wsrc[1 + s];
    }
    int icc = ic >> 5, kg = (ic >> 3) & 3, j = ic & 7;
    int wn2 = oc / 96, mi = (oc % 96) / 16, n15 = oc % 16;
    g_Ks[((((icc * 7) + t) * 12 + mi * 2 + wn2) * 64 + kg * 16 + n15) * 8 + j]
        = (_Float16)v;
}

// ---------------------------------------------------------------------------
// Kernel 2: transpose x (fp32 [b][ic][y][col]) -> g_xt [b][icc][y][kg][col][j8].
// Wave = one kg (8 channels); lane = column PAIR. Loads: float2 per plane
// (512B/wave-instr). Stores: 2 adjacent f16x8 per lane = 32B/lane, 2KB
// contiguous per wave-instr. No LDS.
// ---------------------------------------------------------------------------
__global__ __launch_bounds__(256) void transpose_kernel(const float* __restrict__ x) {
    int id  = blockIdx.x;                 // 8*6*66 = 3168 blocks
    int y   = id % 66;
    int icc = (id / 66) % 6;
    int b   = id / 396;
    int kg   = threadIdx.x >> 6;
    int lane = threadIdx.x & 63;
    const float* src0 = x + ((size_t)b * NIC + icc * 32 + kg * 8) * HPWP + (size_t)y * WP;
    _Float16* dst = g_xt + ((((size_t)(b * 6 + icc) * 66 + y) * 4 + kg) * 322) * 8;
#pragma unroll
    for (int p = 0; p < 3; p++) {
        int c2 = lane + p * 64;           // column pair index, 161 pairs = 322 cols
        if (p < 2 || c2 < 161) {
            float2 v[8];
#pragma unroll
            for (int j = 0; j < 8; j++)
                v[j] = *(const float2*)(src0 + (size_t)j * HPWP + c2 * 2);
            union { f16x8 a; _Float16 h[8]; } u0, u1;
#pragma unroll
            for (int j = 0; j < 8; j++) {
                u0.h[j] = (_Float16)v[j].x;
                u1.h[j] = (_Float16)v[j].y;
            }
            *(f16x8*)&dst[(c2 * 2 + 0) * 8] = u0.a;
            *(f16x8*)&dst[(c2 * 2 + 1) * 8] = u1.a;
        }
    }
}

// ---------------------------------------------------------------------------
// Kernel 3: MFMA implicit-GEMM conv.
// A (weights): global->VGPR, prefetched one tap ahead (contiguous 1KB/frag,
//   L1/L2-hot g_Ks; no LDS round-trip).
// B (x): double-buffered LDS slab per icc [row4][kg4][col66][j8] (+64 pad),
//   staged via global_load_lds ~7 steps ahead.
// ONE __syncthreads per icc (B buffer flip). No manual vmcnt. setprio on MFMA.
// Hex taps (hy,hx): 0:(1,1) 1:(0,0) 2:(0,1) 3:(1,2) 4:(2,2) 5:(2,1) 6:(1,0)
// ---------------------------------------------------------------------------
__device__ __forceinline__ void gload16(const _Float16* g, _Float16* l) {
    __builtin_amdgcn_global_load_lds(
        (const __attribute__((address_space(1))) void*)g,
        (__attribute__((address_space(3))) void*)l, 16, 0, 0);
}

__global__ __launch_bounds__(256, 2) void conv_kernel(
    const float* __restrict__ bias, float* __restrict__ out) {
    __shared__ __align__(16) _Float16 lB[2][8960];   // 2 x 17,920B (1056+64 pad)

    int id = blockIdx.x;                  // 1280 blocks = 8 XCD * 160
    id = (id & 7) * 160 + (id >> 3);      // bijective XCD swizzle: XCD i owns b=i
    int xt5 = id % 5;
    int yt = (id / 5) % 32;
    int b  = id / 160;
    int px0 = xt5 * 64, py0 = yt * 2;

    int tid = threadIdx.x;
    int wave = tid >> 6;
    int lane = tid & 63;
    int kg = lane >> 4, n15 = lane & 15;
    int wm = wave & 1;                    // output row py0+1+wm
    int wn = wave >> 1;                   // oc half (wn*96)

    const int HY[7] = {1, 0, 0, 1, 2, 2, 1};
    const int HX[7] = {1, 0, 1, 2, 2, 1, 0};

    const _Float16* xtb = g_xt + (size_t)b * (6 * ICCH);
    int awo = (wn * 64 + lane) * 8;       // per-thread A-frag offset within slab

    // Precompute B-stage slot decompositions (icc-invariant). 5 uniform issues.
    int gbo[5], lso[5];
#pragma unroll
    for (int k = 0; k < 5; k++) {
        int slot = tid + k * 256;
        if (slot > 1055) slot = 1055;     // clamp: pad region absorbs overflow
        int row = slot / 264;
        int rem = slot % 264;
        int kg2 = rem / 66;
        int col = rem % 66;
        gbo[k] = (((py0 + row) * 4 + kg2) * 322 + px0 + col) * 8;
        lso[k] = slot * 8;
    }

    f32x4 acc[6][4] = {};                 // [oc group][pixel group]
    f16x8 aC[6], aN[6];

    // Prologue: stage B[icc0]; load A[icc0, tap0] into regs.
    {
        const _Float16* bsrc = xtb;
        gload16(bsrc + gbo[0], &lB[0][lso[0]]);
        gload16(bsrc + gbo[1], &lB[0][lso[1]]);
        gload16(bsrc + gbo[2], &lB[0][lso[2]]);
        gload16(bsrc + gbo[3], &lB[0][lso[3]]);
        gload16(bsrc + gbo[4], &lB[0][lso[4]]);
#pragma unroll
        for (int mi = 0; mi < 6; mi++)
            aC[mi] = *(const f16x8*)(g_Ks + awo + mi * 1024);
    }

    int bi = 0;
    for (int icc = 0; icc < 6; icc++) {
        __syncthreads();                  // drains B[bi] staging (vmcnt 0)
        if (icc < 5) {                    // stage B for next icc into lB[bi^1]
            const _Float16* bsrc = xtb + (size_t)(icc + 1) * ICCH;
            gload16(bsrc + gbo[0], &lB[bi ^ 1][lso[0]]);
            gload16(bsrc + gbo[1], &lB[bi ^ 1][lso[1]]);
            gload16(bsrc + gbo[2], &lB[bi ^ 1][lso[2]]);
            gload16(bsrc + gbo[3], &lB[bi ^ 1][lso[3]]);
            gload16(bsrc + gbo[4], &lB[bi ^ 1][lso[4]]);
        }
        const _Float16* ka = g_Ks + icc * (7 * SLABH);
#pragma unroll
        for (int t = 0; t < 7; t++) {
            // Prefetch A for next tap (t==6 -> next icc's tap0, contiguous).
            if (t < 6 || icc < 5) {
                const _Float16* ap = ka + (t + 1) * SLABH + awo;
#pragma unroll
                for (int mi = 0; mi < 6; mi++)
                    aN[mi] = *(const f16x8*)(ap + mi * 1024);
            }
            // B fragments from LDS.
            const _Float16* bb = &lB[bi][(((wm + HY[t]) * 4 + kg) * 66 +
                                          HX[t] + n15) * 8];
            f16x8 xf[4];
#pragma unroll
            for (int ni = 0; ni < 4; ni++)
                xf[ni] = *(const f16x8*)(bb + ni * (16 * 8));
            __builtin_amdgcn_s_setprio(1);
#pragma unroll
            for (int mi = 0; mi < 6; mi++) {
#pragma unroll
                for (int ni = 0; ni < 4; ni++)
                    acc[mi][ni] = __builtin_amdgcn_mfma_f32_16x16x32_f16(
                        aC[mi], xf[ni], acc[mi][ni], 0, 0, 0);
            }
            __builtin_amdgcn_s_setprio(0);
#pragma unroll
            for (int mi = 0; mi < 6; mi++) aC[mi] = aN[mi];
        }
        bi ^= 1;
    }

    // ---- epilogue: +bias, write interior rows ----
    int yo = py0 + 1 + wm;
#pragma unroll
    for (int mi = 0; mi < 6; mi++) {
#pragma unroll
        for (int reg = 0; reg < 4; reg++) {
            int oc = wn * 96 + mi * 16 + kg * 4 + reg;
            float bv = bias[oc / 12];
            size_t base = ((size_t)(b * NOC + oc) * HP + yo) * WP + 1 + px0 + n15;
#pragma unroll
            for (int ni = 0; ni < 4; ni++)
                out[base + ni * 16] = acc[mi][ni][reg] + bv;
        }
    }
}

// ---------------------------------------------------------------------------
// Kernel 4: fill the 1-px ring via twisted-periodic gather from interior.
// ---------------------------------------------------------------------------
__global__ void border_kernel(float* __restrict__ out) {
    int tid = blockIdx.x * 256 + threadIdx.x;   // < 8*192*772 = 1185792
    int r  = tid % 772;
    int bc = tid / 772;
    int ch = bc % NOC;
    int b  = bc / NOC;
    int y, xx;
    if (r < 322)      { y = 0;  xx = r; }
    else if (r < 644) { y = 65; xx = r - 322; }
    else if (r < 708) { xx = 0;   y = r - 644 + 1; }
    else              { xx = 321; y = r - 708 + 1; }
    int t = ch % 12;
    int o12 = ch - t;
    int f = t / 6, rr = t % 6;
    int dt = (xx == 0) ? 1 : ((xx == 321) ? -1 : 0);
    int sx = (xx == 0) ? 320 : ((xx == 321) ? 1 : xx);
    int sy = (y == 0) ? 64 : ((y == 65) ? 1 : y);
    int tsrc = f * 6 + (rr + dt + 6) % 6;
    float v = out[((size_t)(b * NOC + o12 + tsrc) * HP + sy) * WP + sx];
    out[((size_t)(b * NOC + ch) * HP + y) * WP + xx] = v;
}

extern "C" void kernel_launch(void* const* d_in, const int* in_sizes, int n_in,
                              void* d_out, int out_size, void* d_ws, size_t ws_size,
                              hipStream_t stream) {
    const float* x    = (const float*)d_in[0];
    const float* w    = (const float*)d_in[1];
    const float* bias = (const float*)d_in[2];
    float* out = (float*)d_out;

    prep_kernel<<<(7 * NOC * NIC + 255) / 256, 256, 0, stream>>>(w);
    transpose_kernel<<<NB * 6 * 66, 256, 0, stream>>>(x);
    conv_kernel<<<1280, 256, 0, stream>>>(bias, out);
    border_kernel<<<(NB * NOC * 772) / 256, 256, 0, stream>>>(out);
}

// Round 5
// 313.810 us; speedup vs baseline: 1.1229x; 1.0299x over previous
//
#include <hip/hip_runtime.h>

// Problem constants (B=8, Cin=O=16, group=12, H=64)
#define NB   8
#define NIC  192        // Cin*12
#define NOC  192        // O*12
#define HP   66
#define WP   322
#define HPWP (HP * WP)

typedef _Float16 f16x8 __attribute__((ext_vector_type(8)));
typedef float    f32x4 __attribute__((ext_vector_type(4)));

// Swizzled weights: [icc6][tap7][(mi*2+wn)12][lane64][j8]  (516 KB) — L2-resident.
__device__ __align__(16) _Float16 g_Ks[6 * 7 * 12 * 64 * 8];

#define SLABH (12 * 64 * 8)        // halfs per tap slab of g_Ks (6144)

// ---------------------------------------------------------------------------
// Kernel 1: expand weight (O,Cin,12,7) -> g_Ks (f16, MFMA-A-swizzled).
// Slab layout: entry for (kg, oc) lives at [(mi*2+wn)][lane=kg*16+n15][j],
// mi=(oc%96)/16, wn=oc/96, n15=oc%16 -> per-wave A-frag load is 1KB contiguous.
// ---------------------------------------------------------------------------
__global__ void prep_kernel(const float* __restrict__ w) {
    int tid = blockIdx.x * 256 + threadIdx.x;
    if (tid >= 7 * NOC * NIC) return;
    int ic = tid % NIC;
    int rest = tid / NIC;
    int oc = rest % NOC;
    int t = rest / NOC;
    int o = oc / 12, g = oc % 12;
    int c = ic / 12, h = ic % 12;
    int f = g / 6, r = g % 6;
    int ri = (f == 0) ? (6 - r) % 6 : r;          // inv(g).r
    int fh = h / 6, rh = h % 6;
    int pf = f ^ fh;
    int pr = (f == 0) ? (ri + rh) % 6 : (ri - rh + 6) % 6;
    int pm = pf * 6 + pr;                          // perm[g][h]
    const float* wsrc = w + ((o * 16 + c) * 12 + pm) * 7;
    float v;
    if (t == 0) {
        v = wsrc[0];
    } else {
        int i = t - 1;
        int s = (f == 0) ? (i - r + 6) % 6 : (r - i + 6) % 6;
        v = wsrc[1 + s];
    }
    int icc = ic >> 5, kg = (ic >> 3) & 3, j = ic & 7;
    int wn2 = oc / 96, mi = (oc % 96) / 16, n15 = oc % 16;
    g_Ks[((((icc * 7) + t) * 12 + mi * 2 + wn2) * 64 + kg * 16 + n15) * 8 + j]
        = (_Float16)v;
}

// ---------------------------------------------------------------------------
// Kernel 2 (fused conv): MFMA implicit-GEMM conv, reading x DIRECTLY.
// A (weights): global->VGPR, prefetched one tap ahead (contiguous 1KB/frag,
//   L1/L2-hot g_Ks; no LDS round-trip).
// B (x): reg-staged fp32->f16 per icc into double-buffered LDS slab
//   [row4][kg4][col66][j8]: 17 float2 loads + cvt + 34 ds_write_b16 per
//   thread per icc, hidden under the 7-tap MFMA compute. One __syncthreads
//   per icc flips the buffer (writers target lB[bi^1], readers read lB[bi]).
// Hex taps (hy,hx): 0:(1,1) 1:(0,0) 2:(0,1) 3:(1,2) 4:(2,2) 5:(2,1) 6:(1,0)
// ---------------------------------------------------------------------------
__global__ __launch_bounds__(256, 2) void conv_kernel(
    const float* __restrict__ x, const float* __restrict__ bias,
    float* __restrict__ out) {
    __shared__ __align__(16) _Float16 lB[2][8448];   // 2 x 16,896B B slabs

    int id = blockIdx.x;                  // 1280 blocks = 8 XCD * 160
    id = (id & 7) * 160 + (id >> 3);      // bijective XCD swizzle: XCD i owns b=i
    int xt5 = id % 5;
    int yt = (id / 5) % 32;
    int b  = id / 160;
    int px0 = xt5 * 64, py0 = yt * 2;

    int tid = threadIdx.x;
    int wave = tid >> 6;
    int lane = tid & 63;
    int kg = lane >> 4, n15 = lane & 15;
    int wm = wave & 1;                    // output row py0+1+wm
    int wn = wave >> 1;                   // oc half (wn*96)

    const int HY[7] = {1, 0, 0, 1, 2, 2, 1};
    const int HX[7] = {1, 0, 1, 2, 2, 1, 0};

    int awo = (wn * 64 + lane) * 8;       // per-thread A-frag offset within slab

    // ---- per-thread B-staging tables (icc-invariant, unrolled-static) ----
    // slot s = (row*32 + ic)*33 + c covers cols {2c,2c+1} of (row, ic).
    int goff[17];                         // float offset within (b, icc) base
    int lo[17];                           // half offset within LDS slab
#pragma unroll
    for (int k = 0; k < 17; k++) {
        int s = tid + k * 256;
        if (s > 4223) s = 4223;           // clamp: dup loads/writes, same data
        int row = s / 1056;
        int rem = s % 1056;
        int ic  = rem / 33;
        int c2  = rem % 33;
        int kg2 = ic >> 3, j = ic & 7;
        goff[k] = ic * HPWP + row * WP + 2 * c2;
        lo[k]   = (((row * 4 + kg2) * 66) + 2 * c2) * 8 + j;
    }
    const float* xs = x + ((size_t)b * NIC) * HPWP + (size_t)py0 * WP + px0;

#define STAGE(ICC, DST)                                                        \
    {                                                                          \
        const float* _sp = xs + (size_t)(ICC) * 32 * HPWP;                     \
        _Pragma("unroll")                                                      \
        for (int k = 0; k < 17; k++) {                                         \
            float2 v = *(const float2*)(_sp + goff[k]);                        \
            (DST)[lo[k]]     = (_Float16)v.x;                                  \
            (DST)[lo[k] + 8] = (_Float16)v.y;                                  \
        }                                                                      \
    }

    f32x4 acc[6][4] = {};                 // [oc group][pixel group]
    f16x8 aC[6], aN[6];

    // Prologue: stage B[icc0] into lB[0]; load A[icc0, tap0] into regs.
    STAGE(0, lB[0]);
#pragma unroll
    for (int mi = 0; mi < 6; mi++)
        aC[mi] = *(const f16x8*)(g_Ks + awo + mi * 1024);
    __syncthreads();

    int bi = 0;
    for (int icc = 0; icc < 6; icc++) {
        const _Float16* ka = g_Ks + icc * (7 * SLABH);
#pragma unroll
        for (int t = 0; t < 7; t++) {
            // Prefetch A for next tap (t==6 -> next icc's tap0, contiguous).
            if (t < 6 || icc < 5) {
                const _Float16* ap = ka + (t + 1) * SLABH + awo;
#pragma unroll
                for (int mi = 0; mi < 6; mi++)
                    aN[mi] = *(const f16x8*)(ap + mi * 1024);
            }
            // Stage next icc's B slab under the compute (after tap 0 issued).
            if (t == 1 && icc < 5) {
                STAGE(icc + 1, lB[bi ^ 1]);
            }
            // B fragments from LDS.
            const _Float16* bb = &lB[bi][(((wm + HY[t]) * 4 + kg) * 66 +
                                          HX[t] + n15) * 8];
            f16x8 xf[4];
#pragma unroll
            for (int ni = 0; ni < 4; ni++)
                xf[ni] = *(const f16x8*)(bb + ni * (16 * 8));
            __builtin_amdgcn_s_setprio(1);
#pragma unroll
            for (int mi = 0; mi < 6; mi++) {
#pragma unroll
                for (int ni = 0; ni < 4; ni++)
                    acc[mi][ni] = __builtin_amdgcn_mfma_f32_16x16x32_f16(
                        aC[mi], xf[ni], acc[mi][ni], 0, 0, 0);
            }
            __builtin_amdgcn_s_setprio(0);
#pragma unroll
            for (int mi = 0; mi < 6; mi++) aC[mi] = aN[mi];
        }
        __syncthreads();                  // B buffer flip
        bi ^= 1;
    }

    // ---- epilogue: +bias, write interior rows ----
    int yo = py0 + 1 + wm;
#pragma unroll
    for (int mi = 0; mi < 6; mi++) {
#pragma unroll
        for (int reg = 0; reg < 4; reg++) {
            int oc = wn * 96 + mi * 16 + kg * 4 + reg;
            float bv = bias[oc / 12];
            size_t base = ((size_t)(b * NOC + oc) * HP + yo) * WP + 1 + px0 + n15;
#pragma unroll
            for (int ni = 0; ni < 4; ni++)
                out[base + ni * 16] = acc[mi][ni][reg] + bv;
        }
    }
#undef STAGE
}

// ---------------------------------------------------------------------------
// Kernel 3: fill the 1-px ring via twisted-periodic gather from interior.
// ---------------------------------------------------------------------------
__global__ void border_kernel(float* __restrict__ out) {
    int tid = blockIdx.x * 256 + threadIdx.x;   // < 8*192*772 = 1185792
    int r  = tid % 772;
    int bc = tid / 772;
    int ch = bc % NOC;
    int b  = bc / NOC;
    int y, xx;
    if (r < 322)      { y = 0;  xx = r; }
    else if (r < 644) { y = 65; xx = r - 322; }
    else if (r < 708) { xx = 0;   y = r - 644 + 1; }
    else              { xx = 321; y = r - 708 + 1; }
    int t = ch % 12;
    int o12 = ch - t;
    int f = t / 6, rr = t % 6;
    int dt = (xx == 0) ? 1 : ((xx == 321) ? -1 : 0);
    int sx = (xx == 0) ? 320 : ((xx == 321) ? 1 : xx);
    int sy = (y == 0) ? 64 : ((y == 65) ? 1 : y);
    int tsrc = f * 6 + (rr + dt + 6) % 6;
    float v = out[((size_t)(b * NOC + o12 + tsrc) * HP + sy) * WP + sx];
    out[((size_t)(b * NOC + ch) * HP + y) * WP + xx] = v;
}

extern "C" void kernel_launch(void* const* d_in, const int* in_sizes, int n_in,
                              void* d_out, int out_size, void* d_ws, size_t ws_size,
                              hipStream_t stream) {
    const float* x    = (const float*)d_in[0];
    const float* w    = (const float*)d_in[1];
    const float* bias = (const float*)d_in[2];
    float* out = (float*)d_out;

    prep_kernel<<<(7 * NOC * NIC + 255) / 256, 256, 0, stream>>>(w);
    conv_kernel<<<1280, 256, 0, stream>>>(x, bias, out);
    border_kernel<<<(NB * NOC * 772) / 256, 256, 0, stream>>>(out);
}